// Round 1
// baseline (2162.458 us; speedup 1.0000x reference)
//
#include <hip/hip_runtime.h>

// ---------------- CSR build ----------------

__global__ __launch_bounds__(256) void hist_kernel(
    const int* __restrict__ ei_it, const int* __restrict__ ei_tp,
    int E_it, int E_tp, int* __restrict__ deg_it, int* __restrict__ deg_tp)
{
    int i = blockIdx.x * 256 + threadIdx.x;
    if (i < E_it) {
        atomicAdd(&deg_it[ei_it[E_it + i]], 1);
    } else if (i < E_it + E_tp) {
        int e = i - E_it;
        atomicAdd(&deg_tp[ei_tp[E_tp + e]], 1);
    }
}

__global__ __launch_bounds__(256) void alloc_kernel(
    int n, const int* __restrict__ deg_it, const int* __restrict__ deg_tp,
    int* __restrict__ row_it, int* __restrict__ next_it,
    int* __restrict__ row_tp, int* __restrict__ next_tp,
    float* __restrict__ inv_cnt, int* __restrict__ ctr)
{
    int i = blockIdx.x * 256 + threadIdx.x;
    if (i >= n) return;
    int d  = deg_it[i];
    int r  = atomicAdd(&ctr[0], d);
    row_it[i] = r; next_it[i] = r;
    inv_cnt[i] = 1.0f / (float)max(d, 1);
    int d2 = deg_tp[i];
    int r2 = atomicAdd(&ctr[1], d2);
    row_tp[i] = r2; next_tp[i] = r2;
}

__global__ __launch_bounds__(256) void fill_kernel(
    const int* __restrict__ ei_it, const int* __restrict__ ei_tp,
    int E_it, int E_tp,
    int* __restrict__ next_it, int* __restrict__ next_tp,
    int* __restrict__ col_it, int* __restrict__ col_tp)
{
    int i = blockIdx.x * 256 + threadIdx.x;
    if (i < E_it) {
        int src = ei_it[i];
        int dst = ei_it[E_it + i];
        col_it[atomicAdd(&next_it[dst], 1)] = src;
    } else if (i < E_it + E_tp) {
        int e = i - E_it;
        int src = ei_tp[e];
        int dst = ei_tp[E_tp + e];
        col_tp[atomicAdd(&next_tp[dst], 1)] = src;
    }
}

// ---------------- Aggregation: agg[i] = [sum_tp(h_j) | inv_cnt*sum_it(h_j)] ----------------
// 32 lanes per node (lane = channel), 8 nodes per 256-thread block. No LDS, no barriers.

template <int CI>
__global__ __launch_bounds__(256) void agg_kernel(
    int n, const float* __restrict__ hin,
    const int* __restrict__ row_it, const int* __restrict__ deg_it, const int* __restrict__ col_it,
    const int* __restrict__ row_tp, const int* __restrict__ deg_tp, const int* __restrict__ col_tp,
    const float* __restrict__ inv_cnt, float* __restrict__ agg)
{
    int g = threadIdx.x >> 5;
    int c = threadIdx.x & 31;
    int node = blockIdx.x * 8 + g;
    if (node >= n) return;
    if (c >= CI) return;

    float aA = 0.f;
    {
        int rs = row_tp[node], d = deg_tp[node];
        for (int e = 0; e < d; e++) {
            int j = col_tp[rs + e];
            aA += hin[(size_t)j * CI + c];
        }
    }
    float aM = 0.f;
    {
        int rs = row_it[node], d = deg_it[node];
        for (int e = 0; e < d; e++) {
            int j = col_it[rs + e];
            aM += hin[(size_t)j * CI + c];
        }
    }
    aM *= inv_cnt[node];
    agg[(size_t)node * (2 * CI) + c]      = aA;
    agg[(size_t)node * (2 * CI) + CI + c] = aM;
}

// ---------------- Per-layer GEMM: hout = relu([aggA|aggM|hin] @ Wcat + bias (+ hin)) ----------------
// K = 3*CI. Block: 128 threads, tile 256 nodes x 32 cols, per-thread 8n x 8c.

template <int CI, bool RESID>
__global__ __launch_bounds__(128) void gemm_kernel(
    int n, const float* __restrict__ agg, const float* __restrict__ hin,
    const float* __restrict__ Wrel0, const float* __restrict__ Wrel1,
    const float* __restrict__ Wroot0, const float* __restrict__ Wroot1,
    const float* __restrict__ bias0, const float* __restrict__ bias1,
    float* __restrict__ hout)
{
    constexpr int K  = 3 * CI;
    constexpr int KC = (CI == 6) ? 18 : 16;   // K % KC == 0 in both cases
    constexpr int NCHUNK = K / KC;
    constexpr int LDA = 260;                  // 256 + 4: keeps 16B alignment, 2-way-max bank alias

    __shared__ float sW[K * 32];
    __shared__ float sB[32];
    __shared__ float sA[KC * LDA];

    const int tid = threadIdx.x;
    for (int idx = tid; idx < K * 32; idx += 128) {
        int k = idx >> 5, co = idx & 31;
        float w;
        if (k < CI)            w = Wrel0[k * 32 + co];
        else if (k < 2 * CI)   w = Wrel1[(k - CI) * 32 + co];
        else                   w = Wroot0[(k - 2 * CI) * 32 + co] + Wroot1[(k - 2 * CI) * 32 + co];
        sW[idx] = w;
    }
    if (tid < 32) sB[tid] = bias0[tid] + bias1[tid];

    const int n0 = blockIdx.x * 256;
    const int cg = tid & 3;    // 4 col groups x 8 cols
    const int ng = tid >> 2;   // 32 node groups x 8 nodes

    float acc[8][8];
#pragma unroll
    for (int i = 0; i < 8; i++)
#pragma unroll
        for (int j = 0; j < 8; j++) acc[i][j] = 0.f;

    for (int ch = 0; ch < NCHUNK; ch++) {
        const int k0 = ch * KC;
        __syncthreads();
        // stage A chunk [k0, k0+KC) x [n0, n0+256) transposed into LDS
        for (int idx = tid; idx < KC * 256; idx += 128) {
            int kk, nn;
            if constexpr ((KC & (KC - 1)) == 0) { kk = idx & (KC - 1); nn = idx >> 4; }
            else                                { kk = idx % KC;       nn = idx / KC; }
            int node = n0 + nn;
            int k = k0 + kk;
            float v = 0.f;
            if (node < n) {
                v = (k < 2 * CI) ? agg[(size_t)node * (2 * CI) + k]
                                 : hin[(size_t)node * CI + (k - 2 * CI)];
            }
            sA[kk * LDA + nn] = v;
        }
        __syncthreads();
#pragma unroll
        for (int kk = 0; kk < KC; kk++) {
            const float4 a0 = *(const float4*)&sA[kk * LDA + ng * 8];
            const float4 a1 = *(const float4*)&sA[kk * LDA + ng * 8 + 4];
            const int k = k0 + kk;
            const float4 w0 = *(const float4*)&sW[k * 32 + cg * 8];
            const float4 w1 = *(const float4*)&sW[k * 32 + cg * 8 + 4];
            const float av[8] = {a0.x, a0.y, a0.z, a0.w, a1.x, a1.y, a1.z, a1.w};
            const float wv[8] = {w0.x, w0.y, w0.z, w0.w, w1.x, w1.y, w1.z, w1.w};
#pragma unroll
            for (int i = 0; i < 8; i++)
#pragma unroll
                for (int j = 0; j < 8; j++) acc[i][j] += av[i] * wv[j];
        }
    }

    const int cbase = cg * 8;
#pragma unroll
    for (int i = 0; i < 8; i++) {
        int node = n0 + ng * 8 + i;
        if (node < n) {
            float r[8];
#pragma unroll
            for (int j = 0; j < 8; j++) r[j] = acc[i][j] + sB[cbase + j];
            if (RESID) {
                const float4 h0 = *(const float4*)&hin[(size_t)node * 32 + cbase];
                const float4 h1 = *(const float4*)&hin[(size_t)node * 32 + cbase + 4];
                r[0] += h0.x; r[1] += h0.y; r[2] += h0.z; r[3] += h0.w;
                r[4] += h1.x; r[5] += h1.y; r[6] += h1.z; r[7] += h1.w;
            }
#pragma unroll
            for (int j = 0; j < 8; j++) r[j] = fmaxf(r[j], 0.f);
            *(float4*)&hout[(size_t)node * 32 + cbase]     = make_float4(r[0], r[1], r[2], r[3]);
            *(float4*)&hout[(size_t)node * 32 + cbase + 4] = make_float4(r[4], r[5], r[6], r[7]);
        }
    }
}

// ---------------- Final linear: out = h @ Wout + bout  (N x 32 @ 32 x 128) ----------------
// Block: 256 threads, tile 128 nodes x 128 cols, per-thread 8n x 8c.

__global__ __launch_bounds__(256) void final_kernel(
    int n, const float* __restrict__ h, const float* __restrict__ Wout,
    const float* __restrict__ bout, float* __restrict__ out)
{
    constexpr int LDH = 136;  // 128 + 8: 16B-aligned rows, 2-way-max bank alias
    __shared__ float sW[32 * 128];
    __shared__ float sB[128];
    __shared__ float sHT[32 * LDH];

    const int tid = threadIdx.x;
    for (int idx = tid; idx < 4096; idx += 256) sW[idx] = Wout[idx];
    if (tid < 128) sB[tid] = bout[tid];

    const int n0 = blockIdx.x * 128;
    for (int idx = tid; idx < 4096; idx += 256) {
        int k = idx & 31, nn = idx >> 5;
        int node = n0 + nn;
        sHT[k * LDH + nn] = (node < n) ? h[(size_t)node * 32 + k] : 0.f;
    }
    __syncthreads();

    const int cg = tid & 15;   // 16 col groups x 8 cols
    const int ng = tid >> 4;   // 16 node groups x 8 nodes
    float acc[8][8];
#pragma unroll
    for (int i = 0; i < 8; i++)
#pragma unroll
        for (int j = 0; j < 8; j++) acc[i][j] = 0.f;

#pragma unroll
    for (int k = 0; k < 32; k++) {
        const float4 a0 = *(const float4*)&sHT[k * LDH + ng * 8];
        const float4 a1 = *(const float4*)&sHT[k * LDH + ng * 8 + 4];
        const float4 w0 = *(const float4*)&sW[k * 128 + cg * 8];
        const float4 w1 = *(const float4*)&sW[k * 128 + cg * 8 + 4];
        const float av[8] = {a0.x, a0.y, a0.z, a0.w, a1.x, a1.y, a1.z, a1.w};
        const float wv[8] = {w0.x, w0.y, w0.z, w0.w, w1.x, w1.y, w1.z, w1.w};
#pragma unroll
        for (int i = 0; i < 8; i++)
#pragma unroll
            for (int j = 0; j < 8; j++) acc[i][j] += av[i] * wv[j];
    }

    const int cbase = cg * 8;
#pragma unroll
    for (int i = 0; i < 8; i++) {
        int node = n0 + ng * 8 + i;
        if (node < n) {
            float r[8];
#pragma unroll
            for (int j = 0; j < 8; j++) r[j] = acc[i][j] + sB[cbase + j];
            *(float4*)&out[(size_t)node * 128 + cbase]     = make_float4(r[0], r[1], r[2], r[3]);
            *(float4*)&out[(size_t)node * 128 + cbase + 4] = make_float4(r[4], r[5], r[6], r[7]);
        }
    }
}

// ---------------- launch ----------------

extern "C" void kernel_launch(void* const* d_in, const int* in_sizes, int n_in,
                              void* d_out, int out_size, void* d_ws, size_t ws_size,
                              hipStream_t stream)
{
    const float* x      = (const float*)d_in[0];
    const int*   ei_tp  = (const int*)d_in[1];
    const int*   ei_it  = (const int*)d_in[2];
    const float* W0_rel  = (const float*)d_in[3];   // (2,6,32)
    const float* W0_root = (const float*)d_in[4];   // (2,6,32)
    const float* b0      = (const float*)d_in[5];   // (2,32)
    const float* W_rel   = (const float*)d_in[6];   // (4,2,32,32)
    const float* W_root  = (const float*)d_in[7];   // (4,2,32,32)
    const float* b       = (const float*)d_in[8];   // (4,2,32)
    const float* Wout    = (const float*)d_in[9];   // (32,128)
    const float* bout    = (const float*)d_in[10];  // (128,)
    float* out = (float*)d_out;

    const int n    = in_sizes[0] / 6;
    const int E_tp = in_sizes[1] / 2;
    const int E_it = in_sizes[2] / 2;

    // workspace layout (all 4-byte elems)
    float* h0      = (float*)d_ws;                       // n*32
    float* h1      = h0 + (size_t)n * 32;                // n*32
    int*   deg_it  = (int*)(h1 + (size_t)n * 32);        // n   (zeroed)
    int*   deg_tp  = deg_it + n;                         // n   (zeroed)
    int*   ctr     = deg_tp + n;                         // 2   (zeroed)
    int*   row_it  = ctr + 2;                            // n
    int*   next_it = row_it + n;                         // n
    int*   row_tp  = next_it + n;                        // n
    int*   next_tp = row_tp + n;                         // n
    float* inv_cnt = (float*)(next_tp + n);              // n
    int*   col_it  = (int*)(inv_cnt + n);                // E_it
    int*   col_tp  = col_it + E_it;                      // E_tp
    // agg scratch (n*64 floats max = 51.2 MB) lives in d_out (102.4 MB),
    // which is only written by final_kernel after the last GEMM consumed agg.
    float* aggbuf  = (float*)d_out;

    hipMemsetAsync(deg_it, 0, (size_t)(2 * n + 2) * sizeof(int), stream);

    const int eb = (E_it + E_tp + 255) / 256;
    hist_kernel<<<eb, 256, 0, stream>>>(ei_it, ei_tp, E_it, E_tp, deg_it, deg_tp);
    alloc_kernel<<<(n + 255) / 256, 256, 0, stream>>>(n, deg_it, deg_tp, row_it, next_it,
                                                      row_tp, next_tp, inv_cnt, ctr);
    fill_kernel<<<eb, 256, 0, stream>>>(ei_it, ei_tp, E_it, E_tp, next_it, next_tp, col_it, col_tp);

    const int agg_blocks  = (n + 7) / 8;
    const int gemm_blocks = (n + 255) / 256;

    // head: x (N x 6) -> h0
    agg_kernel<6><<<agg_blocks, 256, 0, stream>>>(n, x, row_it, deg_it, col_it,
                                                  row_tp, deg_tp, col_tp, inv_cnt, aggbuf);
    gemm_kernel<6, false><<<gemm_blocks, 128, 0, stream>>>(
        n, aggbuf, x,
        W0_rel, W0_rel + 192, W0_root, W0_root + 192, b0, b0 + 32, h0);

    // 4 residual blocks (32 -> 32), ping-pong h0/h1
    float* hin  = h0;
    float* hout = h1;
    for (int l = 0; l < 4; l++) {
        agg_kernel<32><<<agg_blocks, 256, 0, stream>>>(n, hin, row_it, deg_it, col_it,
                                                       row_tp, deg_tp, col_tp, inv_cnt, aggbuf);
        gemm_kernel<32, true><<<gemm_blocks, 128, 0, stream>>>(
            n, aggbuf, hin,
            W_rel + (size_t)l * 2048, W_rel + (size_t)l * 2048 + 1024,
            W_root + (size_t)l * 2048, W_root + (size_t)l * 2048 + 1024,
            b + (size_t)l * 64, b + (size_t)l * 64 + 32, hout);
        float* t = hin; hin = hout; hout = t;
    }

    // final linear: hin (N x 32) @ Wout (32 x 128) + bout -> out
    final_kernel<<<(n + 127) / 128, 256, 0, stream>>>(n, hin, Wout, bout, out);
}

// Round 2
// 1768.223 us; speedup vs baseline: 1.2230x; 1.2230x over previous
//
#include <hip/hip_runtime.h>

// ---------------- CSR build ----------------

__global__ __launch_bounds__(256) void hist_kernel(
    const int* __restrict__ ei_it, const int* __restrict__ ei_tp,
    int E_it, int E_tp, int* __restrict__ deg_it, int* __restrict__ deg_tp)
{
    int i = blockIdx.x * 256 + threadIdx.x;
    if (i < E_it) {
        atomicAdd(&deg_it[ei_it[E_it + i]], 1);
    } else if (i < E_it + E_tp) {
        int e = i - E_it;
        atomicAdd(&deg_tp[ei_tp[E_tp + e]], 1);
    }
}

__global__ __launch_bounds__(256) void alloc_kernel(
    int n, const int* __restrict__ deg_it, const int* __restrict__ deg_tp,
    int* __restrict__ row_it, int* __restrict__ next_it,
    int* __restrict__ row_tp, int* __restrict__ next_tp,
    float* __restrict__ inv_cnt, int* __restrict__ ctr)
{
    int i = blockIdx.x * 256 + threadIdx.x;
    if (i >= n) return;
    int d  = deg_it[i];
    int r  = atomicAdd(&ctr[0], d);
    row_it[i] = r; next_it[i] = r;
    inv_cnt[i] = 1.0f / (float)max(d, 1);
    int d2 = deg_tp[i];
    int r2 = atomicAdd(&ctr[1], d2);
    row_tp[i] = r2; next_tp[i] = r2;
}

__global__ __launch_bounds__(256) void fill_kernel(
    const int* __restrict__ ei_it, const int* __restrict__ ei_tp,
    int E_it, int E_tp,
    int* __restrict__ next_it, int* __restrict__ next_tp,
    int* __restrict__ col_it, int* __restrict__ col_tp)
{
    int i = blockIdx.x * 256 + threadIdx.x;
    if (i < E_it) {
        int src = ei_it[i];
        int dst = ei_it[E_it + i];
        col_it[atomicAdd(&next_it[dst], 1)] = src;
    } else if (i < E_it + E_tp) {
        int e = i - E_it;
        int src = ei_tp[e];
        int dst = ei_tp[E_tp + e];
        col_tp[atomicAdd(&next_tp[dst], 1)] = src;
    }
}

// ---------------- Aggregation (C=32): one wave per node ----------------
// Lanes: 8 edge-groups x 8 lanes; each lane gathers a float4 (8 lanes cover a
// 128 B row). 8-16 independent row-gathers in flight per wave (vs 1 before).

__global__ __launch_bounds__(256) void agg32_kernel(
    int n, const float* __restrict__ hin,
    const int* __restrict__ row_it, const int* __restrict__ deg_it, const int* __restrict__ col_it,
    const int* __restrict__ row_tp, const int* __restrict__ deg_tp, const int* __restrict__ col_tp,
    const float* __restrict__ inv_cnt, float* __restrict__ agg)
{
    const int wave = threadIdx.x >> 6;   // 4 nodes per block
    const int lane = threadIdx.x & 63;
    const int g = lane >> 3;             // edge group 0..7
    const int q = lane & 7;              // channel quad: c = 4q..4q+3
    const int node = blockIdx.x * 4 + wave;
    if (node >= n) return;

    float4 aA = make_float4(0.f, 0.f, 0.f, 0.f);
    float4 aM = make_float4(0.f, 0.f, 0.f, 0.f);

    {   // temp_previous, aggr = add  (avg degree ~1)
        const int rs = row_tp[node], d = deg_tp[node];
        for (int e = g; e < d; e += 8) {
            const int j = col_tp[rs + e];
            const float4 v = *(const float4*)&hin[(size_t)j * 32 + q * 4];
            aA.x += v.x; aA.y += v.y; aA.z += v.z; aA.w += v.w;
        }
    }
    {   // intersects, aggr = mean  (avg degree ~16), unroll 2
        const int rs = row_it[node], d = deg_it[node];
        int e = g;
        for (; e + 8 < d; e += 16) {
            const int j0 = col_it[rs + e];
            const int j1 = col_it[rs + e + 8];
            const float4 v0 = *(const float4*)&hin[(size_t)j0 * 32 + q * 4];
            const float4 v1 = *(const float4*)&hin[(size_t)j1 * 32 + q * 4];
            aM.x += v0.x + v1.x; aM.y += v0.y + v1.y;
            aM.z += v0.z + v1.z; aM.w += v0.w + v1.w;
        }
        for (; e < d; e += 8) {
            const int j = col_it[rs + e];
            const float4 v = *(const float4*)&hin[(size_t)j * 32 + q * 4];
            aM.x += v.x; aM.y += v.y; aM.z += v.z; aM.w += v.w;
        }
    }

    // combine the 8 edge groups (xor masks don't touch the q bits)
#pragma unroll
    for (int mask = 8; mask < 64; mask <<= 1) {
        aA.x += __shfl_xor(aA.x, mask); aA.y += __shfl_xor(aA.y, mask);
        aA.z += __shfl_xor(aA.z, mask); aA.w += __shfl_xor(aA.w, mask);
        aM.x += __shfl_xor(aM.x, mask); aM.y += __shfl_xor(aM.y, mask);
        aM.z += __shfl_xor(aM.z, mask); aM.w += __shfl_xor(aM.w, mask);
    }

    if (lane < 8) {
        const float ic = inv_cnt[node];
        aM.x *= ic; aM.y *= ic; aM.z *= ic; aM.w *= ic;
        *(float4*)&agg[(size_t)node * 64 + q * 4]      = aA;
        *(float4*)&agg[(size_t)node * 64 + 32 + q * 4] = aM;
    }
}

// ---------------- Aggregation (C=6, head): one wave per node ----------------
// Lanes: 8 edge-groups x 8 lanes (channel = lane&7, active < 6).

__global__ __launch_bounds__(256) void agg6_kernel(
    int n, const float* __restrict__ hin,
    const int* __restrict__ row_it, const int* __restrict__ deg_it, const int* __restrict__ col_it,
    const int* __restrict__ row_tp, const int* __restrict__ deg_tp, const int* __restrict__ col_tp,
    const float* __restrict__ inv_cnt, float* __restrict__ agg)
{
    const int wave = threadIdx.x >> 6;
    const int lane = threadIdx.x & 63;
    const int g = lane >> 3;
    const int c = lane & 7;
    const int cc = (c < 6) ? c : 0;   // keep loads in-bounds; lanes c>=6 never write
    const int node = blockIdx.x * 4 + wave;
    if (node >= n) return;

    float aA = 0.f, aM = 0.f;
    {
        const int rs = row_tp[node], d = deg_tp[node];
        for (int e = g; e < d; e += 8) {
            const int j = col_tp[rs + e];
            aA += hin[(size_t)j * 6 + cc];
        }
    }
    {
        const int rs = row_it[node], d = deg_it[node];
        int e = g;
        for (; e + 8 < d; e += 16) {
            const int j0 = col_it[rs + e];
            const int j1 = col_it[rs + e + 8];
            aM += hin[(size_t)j0 * 6 + cc] + hin[(size_t)j1 * 6 + cc];
        }
        for (; e < d; e += 8) {
            const int j = col_it[rs + e];
            aM += hin[(size_t)j * 6 + cc];
        }
    }

#pragma unroll
    for (int mask = 8; mask < 64; mask <<= 1) {
        aA += __shfl_xor(aA, mask);
        aM += __shfl_xor(aM, mask);
    }

    if (lane < 6) {
        agg[(size_t)node * 12 + c]     = aA;
        agg[(size_t)node * 12 + 6 + c] = aM * inv_cnt[node];
    }
}

// ---------------- Per-layer GEMM: hout = relu([aggA|aggM|hin] @ Wcat + bias (+ hin)) ----------------

template <int CI, bool RESID>
__global__ __launch_bounds__(128) void gemm_kernel(
    int n, const float* __restrict__ agg, const float* __restrict__ hin,
    const float* __restrict__ Wrel0, const float* __restrict__ Wrel1,
    const float* __restrict__ Wroot0, const float* __restrict__ Wroot1,
    const float* __restrict__ bias0, const float* __restrict__ bias1,
    float* __restrict__ hout)
{
    constexpr int K  = 3 * CI;
    constexpr int KC = (CI == 6) ? 18 : 16;
    constexpr int NCHUNK = K / KC;
    constexpr int LDA = 260;

    __shared__ float sW[K * 32];
    __shared__ float sB[32];
    __shared__ float sA[KC * LDA];

    const int tid = threadIdx.x;
    for (int idx = tid; idx < K * 32; idx += 128) {
        int k = idx >> 5, co = idx & 31;
        float w;
        if (k < CI)            w = Wrel0[k * 32 + co];
        else if (k < 2 * CI)   w = Wrel1[(k - CI) * 32 + co];
        else                   w = Wroot0[(k - 2 * CI) * 32 + co] + Wroot1[(k - 2 * CI) * 32 + co];
        sW[idx] = w;
    }
    if (tid < 32) sB[tid] = bias0[tid] + bias1[tid];

    const int n0 = blockIdx.x * 256;
    const int cg = tid & 3;
    const int ng = tid >> 2;

    float acc[8][8];
#pragma unroll
    for (int i = 0; i < 8; i++)
#pragma unroll
        for (int j = 0; j < 8; j++) acc[i][j] = 0.f;

    for (int ch = 0; ch < NCHUNK; ch++) {
        const int k0 = ch * KC;
        __syncthreads();
        for (int idx = tid; idx < KC * 256; idx += 128) {
            int kk, nn;
            if constexpr ((KC & (KC - 1)) == 0) { kk = idx & (KC - 1); nn = idx >> 4; }
            else                                { kk = idx % KC;       nn = idx / KC; }
            int node = n0 + nn;
            int k = k0 + kk;
            float v = 0.f;
            if (node < n) {
                v = (k < 2 * CI) ? agg[(size_t)node * (2 * CI) + k]
                                 : hin[(size_t)node * CI + (k - 2 * CI)];
            }
            sA[kk * LDA + nn] = v;
        }
        __syncthreads();
#pragma unroll
        for (int kk = 0; kk < KC; kk++) {
            const float4 a0 = *(const float4*)&sA[kk * LDA + ng * 8];
            const float4 a1 = *(const float4*)&sA[kk * LDA + ng * 8 + 4];
            const int k = k0 + kk;
            const float4 w0 = *(const float4*)&sW[k * 32 + cg * 8];
            const float4 w1 = *(const float4*)&sW[k * 32 + cg * 8 + 4];
            const float av[8] = {a0.x, a0.y, a0.z, a0.w, a1.x, a1.y, a1.z, a1.w};
            const float wv[8] = {w0.x, w0.y, w0.z, w0.w, w1.x, w1.y, w1.z, w1.w};
#pragma unroll
            for (int i = 0; i < 8; i++)
#pragma unroll
                for (int j = 0; j < 8; j++) acc[i][j] += av[i] * wv[j];
        }
    }

    const int cbase = cg * 8;
#pragma unroll
    for (int i = 0; i < 8; i++) {
        int node = n0 + ng * 8 + i;
        if (node < n) {
            float r[8];
#pragma unroll
            for (int j = 0; j < 8; j++) r[j] = acc[i][j] + sB[cbase + j];
            if (RESID) {
                const float4 h0 = *(const float4*)&hin[(size_t)node * 32 + cbase];
                const float4 h1 = *(const float4*)&hin[(size_t)node * 32 + cbase + 4];
                r[0] += h0.x; r[1] += h0.y; r[2] += h0.z; r[3] += h0.w;
                r[4] += h1.x; r[5] += h1.y; r[6] += h1.z; r[7] += h1.w;
            }
#pragma unroll
            for (int j = 0; j < 8; j++) r[j] = fmaxf(r[j], 0.f);
            *(float4*)&hout[(size_t)node * 32 + cbase]     = make_float4(r[0], r[1], r[2], r[3]);
            *(float4*)&hout[(size_t)node * 32 + cbase + 4] = make_float4(r[4], r[5], r[6], r[7]);
        }
    }
}

// ---------------- Final linear: out = h @ Wout + bout ----------------

__global__ __launch_bounds__(256) void final_kernel(
    int n, const float* __restrict__ h, const float* __restrict__ Wout,
    const float* __restrict__ bout, float* __restrict__ out)
{
    constexpr int LDH = 136;
    __shared__ float sW[32 * 128];
    __shared__ float sB[128];
    __shared__ float sHT[32 * LDH];

    const int tid = threadIdx.x;
    for (int idx = tid; idx < 4096; idx += 256) sW[idx] = Wout[idx];
    if (tid < 128) sB[tid] = bout[tid];

    const int n0 = blockIdx.x * 128;
    for (int idx = tid; idx < 4096; idx += 256) {
        int k = idx & 31, nn = idx >> 5;
        int node = n0 + nn;
        sHT[k * LDH + nn] = (node < n) ? h[(size_t)node * 32 + k] : 0.f;
    }
    __syncthreads();

    const int cg = tid & 15;
    const int ng = tid >> 4;
    float acc[8][8];
#pragma unroll
    for (int i = 0; i < 8; i++)
#pragma unroll
        for (int j = 0; j < 8; j++) acc[i][j] = 0.f;

#pragma unroll
    for (int k = 0; k < 32; k++) {
        const float4 a0 = *(const float4*)&sHT[k * LDH + ng * 8];
        const float4 a1 = *(const float4*)&sHT[k * LDH + ng * 8 + 4];
        const float4 w0 = *(const float4*)&sW[k * 128 + cg * 8];
        const float4 w1 = *(const float4*)&sW[k * 128 + cg * 8 + 4];
        const float av[8] = {a0.x, a0.y, a0.z, a0.w, a1.x, a1.y, a1.z, a1.w};
        const float wv[8] = {w0.x, w0.y, w0.z, w0.w, w1.x, w1.y, w1.z, w1.w};
#pragma unroll
        for (int i = 0; i < 8; i++)
#pragma unroll
            for (int j = 0; j < 8; j++) acc[i][j] += av[i] * wv[j];
    }

    const int cbase = cg * 8;
#pragma unroll
    for (int i = 0; i < 8; i++) {
        int node = n0 + ng * 8 + i;
        if (node < n) {
            float r[8];
#pragma unroll
            for (int j = 0; j < 8; j++) r[j] = acc[i][j] + sB[cbase + j];
            *(float4*)&out[(size_t)node * 128 + cbase]     = make_float4(r[0], r[1], r[2], r[3]);
            *(float4*)&out[(size_t)node * 128 + cbase + 4] = make_float4(r[4], r[5], r[6], r[7]);
        }
    }
}

// ---------------- launch ----------------

extern "C" void kernel_launch(void* const* d_in, const int* in_sizes, int n_in,
                              void* d_out, int out_size, void* d_ws, size_t ws_size,
                              hipStream_t stream)
{
    const float* x      = (const float*)d_in[0];
    const int*   ei_tp  = (const int*)d_in[1];
    const int*   ei_it  = (const int*)d_in[2];
    const float* W0_rel  = (const float*)d_in[3];
    const float* W0_root = (const float*)d_in[4];
    const float* b0      = (const float*)d_in[5];
    const float* W_rel   = (const float*)d_in[6];
    const float* W_root  = (const float*)d_in[7];
    const float* b       = (const float*)d_in[8];
    const float* Wout    = (const float*)d_in[9];
    const float* bout    = (const float*)d_in[10];
    float* out = (float*)d_out;

    const int n    = in_sizes[0] / 6;
    const int E_tp = in_sizes[1] / 2;
    const int E_it = in_sizes[2] / 2;

    float* h0      = (float*)d_ws;
    float* h1      = h0 + (size_t)n * 32;
    int*   deg_it  = (int*)(h1 + (size_t)n * 32);
    int*   deg_tp  = deg_it + n;
    int*   ctr     = deg_tp + n;
    int*   row_it  = ctr + 2;
    int*   next_it = row_it + n;
    int*   row_tp  = next_it + n;
    int*   next_tp = row_tp + n;
    float* inv_cnt = (float*)(next_tp + n);
    int*   col_it  = (int*)(inv_cnt + n);
    int*   col_tp  = col_it + E_it;
    float* aggbuf  = (float*)d_out;   // consumed before final_kernel writes d_out

    hipMemsetAsync(deg_it, 0, (size_t)(2 * n + 2) * sizeof(int), stream);

    const int eb = (E_it + E_tp + 255) / 256;
    hist_kernel<<<eb, 256, 0, stream>>>(ei_it, ei_tp, E_it, E_tp, deg_it, deg_tp);
    alloc_kernel<<<(n + 255) / 256, 256, 0, stream>>>(n, deg_it, deg_tp, row_it, next_it,
                                                      row_tp, next_tp, inv_cnt, ctr);
    fill_kernel<<<eb, 256, 0, stream>>>(ei_it, ei_tp, E_it, E_tp, next_it, next_tp, col_it, col_tp);

    const int agg_blocks  = (n + 3) / 4;   // 1 wave per node, 4 per block
    const int gemm_blocks = (n + 255) / 256;

    agg6_kernel<<<agg_blocks, 256, 0, stream>>>(n, x, row_it, deg_it, col_it,
                                                row_tp, deg_tp, col_tp, inv_cnt, aggbuf);
    gemm_kernel<6, false><<<gemm_blocks, 128, 0, stream>>>(
        n, aggbuf, x,
        W0_rel, W0_rel + 192, W0_root, W0_root + 192, b0, b0 + 32, h0);

    float* hin  = h0;
    float* hout = h1;
    for (int l = 0; l < 4; l++) {
        agg32_kernel<<<agg_blocks, 256, 0, stream>>>(n, hin, row_it, deg_it, col_it,
                                                     row_tp, deg_tp, col_tp, inv_cnt, aggbuf);
        gemm_kernel<32, true><<<gemm_blocks, 128, 0, stream>>>(
            n, aggbuf, hin,
            W_rel + (size_t)l * 2048, W_rel + (size_t)l * 2048 + 1024,
            W_root + (size_t)l * 2048, W_root + (size_t)l * 2048 + 1024,
            b + (size_t)l * 64, b + (size_t)l * 64 + 32, hout);
        float* t = hin; hin = hout; hout = t;
    }

    final_kernel<<<(n + 127) / 128, 256, 0, stream>>>(n, hin, Wout, bout, out);
}

// Round 3
// 1521.349 us; speedup vs baseline: 1.4214x; 1.1623x over previous
//
#include <hip/hip_runtime.h>

// n must be <= 256*1024 for the bucket scheme (bucket = dst >> 10, B <= 256).

// ---------------- CSR build: tp (small, 200K edges) — old path ----------------

__global__ __launch_bounds__(256) void hist_tp_kernel(
    const int* __restrict__ ei_tp, int E_tp, int* __restrict__ deg_tp)
{
    int i = blockIdx.x * 256 + threadIdx.x;
    if (i < E_tp) atomicAdd(&deg_tp[ei_tp[E_tp + i]], 1);
}

__global__ __launch_bounds__(256) void alloc_tp_kernel(
    int n, const int* __restrict__ deg_tp,
    int* __restrict__ row_tp, int* __restrict__ next_tp, int* __restrict__ ctr)
{
    int i = blockIdx.x * 256 + threadIdx.x;
    if (i >= n) return;
    int d = deg_tp[i];
    int r = atomicAdd(&ctr[0], d);
    row_tp[i] = r; next_tp[i] = r;
}

__global__ __launch_bounds__(256) void fill_tp_kernel(
    const int* __restrict__ ei_tp, int E_tp,
    int* __restrict__ next_tp, int* __restrict__ col_tp)
{
    int i = blockIdx.x * 256 + threadIdx.x;
    if (i >= E_tp) return;
    int src = ei_tp[i];
    int dst = ei_tp[E_tp + i];
    col_tp[atomicAdd(&next_tp[dst], 1)] = src;
}

// ---------------- CSR build: it (3.2M edges) — two-level multisplit ----------------

__global__ __launch_bounds__(256) void bucket_count_kernel(
    const int* __restrict__ ei_it, int E_it, int B, int* __restrict__ bcnt)
{
    __shared__ int h[256];
    h[threadIdx.x] = 0;
    __syncthreads();
    const int stride = gridDim.x * 256;
    for (int i = blockIdx.x * 256 + threadIdx.x; i < E_it; i += stride)
        atomicAdd(&h[ei_it[E_it + i] >> 10], 1);
    __syncthreads();
    int v = h[threadIdx.x];
    if (threadIdx.x < B && v) atomicAdd(&bcnt[threadIdx.x], v);
}

__global__ __launch_bounds__(256) void bucket_prefix_kernel(
    int B, const int* __restrict__ bcnt, int* __restrict__ bbase, int* __restrict__ bcursor)
{
    __shared__ int s[256];
    const int t = threadIdx.x;
    s[t] = (t < B) ? bcnt[t] : 0;
    __syncthreads();
    for (int off = 1; off < 256; off <<= 1) {
        int v = (t >= off) ? s[t - off] : 0;
        __syncthreads();
        if (t >= off) s[t] += v;
        __syncthreads();
    }
    if (t == 0) bbase[0] = 0;
    if (t < B) {
        bbase[t + 1] = s[t];
        bcursor[t] = s[t] - bcnt[t];
    }
}

// One block per 2048-edge tile: LDS rank within (tile,bucket), one global atomic
// per (tile,bucket), then write packed (dst,src) into contiguous per-bucket runs.
__global__ __launch_bounds__(256) void multisplit_kernel(
    const int* __restrict__ ei_it, int E_it,
    int* __restrict__ bcursor, unsigned long long* __restrict__ ebuf)
{
    __shared__ int cnt[256];
    __shared__ int gbase[256];
    const int tid  = threadIdx.x;
    const int base = blockIdx.x * 2048;
    cnt[tid] = 0;
    __syncthreads();

    int src[8], dst[8], rk[8], bk[8];
#pragma unroll
    for (int k = 0; k < 8; k++) {
        int i = base + k * 256 + tid;
        if (i < E_it) {
            src[k] = ei_it[i];
            dst[k] = ei_it[E_it + i];
            bk[k]  = dst[k] >> 10;
            rk[k]  = atomicAdd(&cnt[bk[k]], 1);
        } else rk[k] = -1;
    }
    __syncthreads();
    int c = cnt[tid];
    if (c) gbase[tid] = atomicAdd(&bcursor[tid], c);
    __syncthreads();
#pragma unroll
    for (int k = 0; k < 8; k++) {
        if (rk[k] >= 0) {
            int pos = gbase[bk[k]] + rk[k];
            ebuf[pos] = ((unsigned long long)(unsigned)dst[k] << 32) | (unsigned)src[k];
        }
    }
}

// One block per bucket: local degree count + LDS scan -> row/deg/inv_cnt
// (coalesced), then scatter col within the bucket's compact region (one CU).
__global__ __launch_bounds__(256) void csr_it_kernel(
    int n, const unsigned long long* __restrict__ ebuf, const int* __restrict__ bbase,
    int* __restrict__ row_it, int* __restrict__ deg_it,
    float* __restrict__ inv_cnt, int* __restrict__ col_it)
{
    __shared__ int ldeg[1024];
    __shared__ int lnext[1024];
    __shared__ int lpart[256];
    const int b = blockIdx.x;
    const int t = threadIdx.x;
    const int node_lo = b << 10;
    const int nn = min(1024, n - node_lo);
    const int e0 = bbase[b], e1 = bbase[b + 1];

    for (int i = t; i < nn; i += 256) ldeg[i] = 0;
    __syncthreads();
    for (int i = e0 + t; i < e1; i += 256)
        atomicAdd(&ldeg[(int)(ebuf[i] >> 32) - node_lo], 1);
    __syncthreads();

    // exclusive scan over nn (<=1024) entries: 4/thread + 256-wide Hillis-Steele
    const int i4 = 4 * t;
    int l0 = (i4     < nn) ? ldeg[i4]     : 0;
    int l1 = (i4 + 1 < nn) ? ldeg[i4 + 1] : 0;
    int l2 = (i4 + 2 < nn) ? ldeg[i4 + 2] : 0;
    int l3 = (i4 + 3 < nn) ? ldeg[i4 + 3] : 0;
    const int lsum = l0 + l1 + l2 + l3;
    lpart[t] = lsum;
    __syncthreads();
    for (int off = 1; off < 256; off <<= 1) {
        int v = (t >= off) ? lpart[t - off] : 0;
        __syncthreads();
        if (t >= off) lpart[t] += v;
        __syncthreads();
    }
    const int ex = lpart[t] - lsum;

    const int p[4] = {ex, ex + l0, ex + l0 + l1, ex + l0 + l1 + l2};
    const int l[4] = {l0, l1, l2, l3};
#pragma unroll
    for (int k = 0; k < 4; k++) {
        int i = i4 + k;
        if (i < nn) {
            lnext[i] = p[k];
            row_it[node_lo + i]  = e0 + p[k];
            deg_it[node_lo + i]  = l[k];
            inv_cnt[node_lo + i] = 1.0f / (float)max(l[k], 1);
        }
    }
    __syncthreads();
    for (int i = e0 + t; i < e1; i += 256) {
        unsigned long long v = ebuf[i];
        int dstl = (int)(v >> 32) - node_lo;
        int pos  = atomicAdd(&lnext[dstl], 1);
        col_it[e0 + pos] = (int)(v & 0xffffffffu);
    }
}

// ---------------- Aggregation (C=32): one wave per node ----------------

__global__ __launch_bounds__(256) void agg32_kernel(
    int n, const float* __restrict__ hin,
    const int* __restrict__ row_it, const int* __restrict__ deg_it, const int* __restrict__ col_it,
    const int* __restrict__ row_tp, const int* __restrict__ deg_tp, const int* __restrict__ col_tp,
    const float* __restrict__ inv_cnt, float* __restrict__ agg)
{
    const int wave = threadIdx.x >> 6;
    const int lane = threadIdx.x & 63;
    const int g = lane >> 3;
    const int q = lane & 7;
    const int node = blockIdx.x * 4 + wave;
    if (node >= n) return;

    float4 aA = make_float4(0.f, 0.f, 0.f, 0.f);
    float4 aM = make_float4(0.f, 0.f, 0.f, 0.f);

    {
        const int rs = row_tp[node], d = deg_tp[node];
        for (int e = g; e < d; e += 8) {
            const int j = col_tp[rs + e];
            const float4 v = *(const float4*)&hin[(size_t)j * 32 + q * 4];
            aA.x += v.x; aA.y += v.y; aA.z += v.z; aA.w += v.w;
        }
    }
    {
        const int rs = row_it[node], d = deg_it[node];
        int e = g;
        for (; e + 8 < d; e += 16) {
            const int j0 = col_it[rs + e];
            const int j1 = col_it[rs + e + 8];
            const float4 v0 = *(const float4*)&hin[(size_t)j0 * 32 + q * 4];
            const float4 v1 = *(const float4*)&hin[(size_t)j1 * 32 + q * 4];
            aM.x += v0.x + v1.x; aM.y += v0.y + v1.y;
            aM.z += v0.z + v1.z; aM.w += v0.w + v1.w;
        }
        for (; e < d; e += 8) {
            const int j = col_it[rs + e];
            const float4 v = *(const float4*)&hin[(size_t)j * 32 + q * 4];
            aM.x += v.x; aM.y += v.y; aM.z += v.z; aM.w += v.w;
        }
    }

#pragma unroll
    for (int mask = 8; mask < 64; mask <<= 1) {
        aA.x += __shfl_xor(aA.x, mask); aA.y += __shfl_xor(aA.y, mask);
        aA.z += __shfl_xor(aA.z, mask); aA.w += __shfl_xor(aA.w, mask);
        aM.x += __shfl_xor(aM.x, mask); aM.y += __shfl_xor(aM.y, mask);
        aM.z += __shfl_xor(aM.z, mask); aM.w += __shfl_xor(aM.w, mask);
    }

    if (lane < 8) {
        const float ic = inv_cnt[node];
        aM.x *= ic; aM.y *= ic; aM.z *= ic; aM.w *= ic;
        *(float4*)&agg[(size_t)node * 64 + q * 4]      = aA;
        *(float4*)&agg[(size_t)node * 64 + 32 + q * 4] = aM;
    }
}

// ---------------- Aggregation (C=6, head) ----------------

__global__ __launch_bounds__(256) void agg6_kernel(
    int n, const float* __restrict__ hin,
    const int* __restrict__ row_it, const int* __restrict__ deg_it, const int* __restrict__ col_it,
    const int* __restrict__ row_tp, const int* __restrict__ deg_tp, const int* __restrict__ col_tp,
    const float* __restrict__ inv_cnt, float* __restrict__ agg)
{
    const int wave = threadIdx.x >> 6;
    const int lane = threadIdx.x & 63;
    const int g = lane >> 3;
    const int c = lane & 7;
    const int cc = (c < 6) ? c : 0;
    const int node = blockIdx.x * 4 + wave;
    if (node >= n) return;

    float aA = 0.f, aM = 0.f;
    {
        const int rs = row_tp[node], d = deg_tp[node];
        for (int e = g; e < d; e += 8) {
            const int j = col_tp[rs + e];
            aA += hin[(size_t)j * 6 + cc];
        }
    }
    {
        const int rs = row_it[node], d = deg_it[node];
        int e = g;
        for (; e + 8 < d; e += 16) {
            const int j0 = col_it[rs + e];
            const int j1 = col_it[rs + e + 8];
            aM += hin[(size_t)j0 * 6 + cc] + hin[(size_t)j1 * 6 + cc];
        }
        for (; e < d; e += 8) {
            const int j = col_it[rs + e];
            aM += hin[(size_t)j * 6 + cc];
        }
    }

#pragma unroll
    for (int mask = 8; mask < 64; mask <<= 1) {
        aA += __shfl_xor(aA, mask);
        aM += __shfl_xor(aM, mask);
    }

    if (lane < 6) {
        agg[(size_t)node * 12 + c]     = aA;
        agg[(size_t)node * 12 + 6 + c] = aM * inv_cnt[node];
    }
}

// ---------------- Per-layer GEMM ----------------

template <int CI, bool RESID>
__global__ __launch_bounds__(128) void gemm_kernel(
    int n, const float* __restrict__ agg, const float* __restrict__ hin,
    const float* __restrict__ Wrel0, const float* __restrict__ Wrel1,
    const float* __restrict__ Wroot0, const float* __restrict__ Wroot1,
    const float* __restrict__ bias0, const float* __restrict__ bias1,
    float* __restrict__ hout)
{
    constexpr int K  = 3 * CI;
    constexpr int KC = (CI == 6) ? 18 : 16;
    constexpr int NCHUNK = K / KC;
    constexpr int LDA = 260;

    __shared__ float sW[K * 32];
    __shared__ float sB[32];
    __shared__ float sA[KC * LDA];

    const int tid = threadIdx.x;
    for (int idx = tid; idx < K * 32; idx += 128) {
        int k = idx >> 5, co = idx & 31;
        float w;
        if (k < CI)            w = Wrel0[k * 32 + co];
        else if (k < 2 * CI)   w = Wrel1[(k - CI) * 32 + co];
        else                   w = Wroot0[(k - 2 * CI) * 32 + co] + Wroot1[(k - 2 * CI) * 32 + co];
        sW[idx] = w;
    }
    if (tid < 32) sB[tid] = bias0[tid] + bias1[tid];

    const int n0 = blockIdx.x * 256;
    const int cg = tid & 3;
    const int ng = tid >> 2;

    float acc[8][8];
#pragma unroll
    for (int i = 0; i < 8; i++)
#pragma unroll
        for (int j = 0; j < 8; j++) acc[i][j] = 0.f;

    for (int ch = 0; ch < NCHUNK; ch++) {
        const int k0 = ch * KC;
        __syncthreads();
        for (int idx = tid; idx < KC * 256; idx += 128) {
            int kk, nn;
            if constexpr ((KC & (KC - 1)) == 0) { kk = idx & (KC - 1); nn = idx >> 4; }
            else                                { kk = idx % KC;       nn = idx / KC; }
            int node = n0 + nn;
            int k = k0 + kk;
            float v = 0.f;
            if (node < n) {
                v = (k < 2 * CI) ? agg[(size_t)node * (2 * CI) + k]
                                 : hin[(size_t)node * CI + (k - 2 * CI)];
            }
            sA[kk * LDA + nn] = v;
        }
        __syncthreads();
#pragma unroll
        for (int kk = 0; kk < KC; kk++) {
            const float4 a0 = *(const float4*)&sA[kk * LDA + ng * 8];
            const float4 a1 = *(const float4*)&sA[kk * LDA + ng * 8 + 4];
            const int k = k0 + kk;
            const float4 w0 = *(const float4*)&sW[k * 32 + cg * 8];
            const float4 w1 = *(const float4*)&sW[k * 32 + cg * 8 + 4];
            const float av[8] = {a0.x, a0.y, a0.z, a0.w, a1.x, a1.y, a1.z, a1.w};
            const float wv[8] = {w0.x, w0.y, w0.z, w0.w, w1.x, w1.y, w1.z, w1.w};
#pragma unroll
            for (int i = 0; i < 8; i++)
#pragma unroll
                for (int j = 0; j < 8; j++) acc[i][j] += av[i] * wv[j];
        }
    }

    const int cbase = cg * 8;
#pragma unroll
    for (int i = 0; i < 8; i++) {
        int node = n0 + ng * 8 + i;
        if (node < n) {
            float r[8];
#pragma unroll
            for (int j = 0; j < 8; j++) r[j] = acc[i][j] + sB[cbase + j];
            if (RESID) {
                const float4 h0 = *(const float4*)&hin[(size_t)node * 32 + cbase];
                const float4 h1 = *(const float4*)&hin[(size_t)node * 32 + cbase + 4];
                r[0] += h0.x; r[1] += h0.y; r[2] += h0.z; r[3] += h0.w;
                r[4] += h1.x; r[5] += h1.y; r[6] += h1.z; r[7] += h1.w;
            }
#pragma unroll
            for (int j = 0; j < 8; j++) r[j] = fmaxf(r[j], 0.f);
            *(float4*)&hout[(size_t)node * 32 + cbase]     = make_float4(r[0], r[1], r[2], r[3]);
            *(float4*)&hout[(size_t)node * 32 + cbase + 4] = make_float4(r[4], r[5], r[6], r[7]);
        }
    }
}

// ---------------- Final linear ----------------

__global__ __launch_bounds__(256) void final_kernel(
    int n, const float* __restrict__ h, const float* __restrict__ Wout,
    const float* __restrict__ bout, float* __restrict__ out)
{
    constexpr int LDH = 136;
    __shared__ float sW[32 * 128];
    __shared__ float sB[128];
    __shared__ float sHT[32 * LDH];

    const int tid = threadIdx.x;
    for (int idx = tid; idx < 4096; idx += 256) sW[idx] = Wout[idx];
    if (tid < 128) sB[tid] = bout[tid];

    const int n0 = blockIdx.x * 128;
    for (int idx = tid; idx < 4096; idx += 256) {
        int k = idx & 31, nn = idx >> 5;
        int node = n0 + nn;
        sHT[k * LDH + nn] = (node < n) ? h[(size_t)node * 32 + k] : 0.f;
    }
    __syncthreads();

    const int cg = tid & 15;
    const int ng = tid >> 4;
    float acc[8][8];
#pragma unroll
    for (int i = 0; i < 8; i++)
#pragma unroll
        for (int j = 0; j < 8; j++) acc[i][j] = 0.f;

#pragma unroll
    for (int k = 0; k < 32; k++) {
        const float4 a0 = *(const float4*)&sHT[k * LDH + ng * 8];
        const float4 a1 = *(const float4*)&sHT[k * LDH + ng * 8 + 4];
        const float4 w0 = *(const float4*)&sW[k * 128 + cg * 8];
        const float4 w1 = *(const float4*)&sW[k * 128 + cg * 8 + 4];
        const float av[8] = {a0.x, a0.y, a0.z, a0.w, a1.x, a1.y, a1.z, a1.w};
        const float wv[8] = {w0.x, w0.y, w0.z, w0.w, w1.x, w1.y, w1.z, w1.w};
#pragma unroll
        for (int i = 0; i < 8; i++)
#pragma unroll
            for (int j = 0; j < 8; j++) acc[i][j] += av[i] * wv[j];
    }

    const int cbase = cg * 8;
#pragma unroll
    for (int i = 0; i < 8; i++) {
        int node = n0 + ng * 8 + i;
        if (node < n) {
            float r[8];
#pragma unroll
            for (int j = 0; j < 8; j++) r[j] = acc[i][j] + sB[cbase + j];
            *(float4*)&out[(size_t)node * 128 + cbase]     = make_float4(r[0], r[1], r[2], r[3]);
            *(float4*)&out[(size_t)node * 128 + cbase + 4] = make_float4(r[4], r[5], r[6], r[7]);
        }
    }
}

// ---------------- launch ----------------

extern "C" void kernel_launch(void* const* d_in, const int* in_sizes, int n_in,
                              void* d_out, int out_size, void* d_ws, size_t ws_size,
                              hipStream_t stream)
{
    const float* x      = (const float*)d_in[0];
    const int*   ei_tp  = (const int*)d_in[1];
    const int*   ei_it  = (const int*)d_in[2];
    const float* W0_rel  = (const float*)d_in[3];
    const float* W0_root = (const float*)d_in[4];
    const float* b0      = (const float*)d_in[5];
    const float* W_rel   = (const float*)d_in[6];
    const float* W_root  = (const float*)d_in[7];
    const float* b       = (const float*)d_in[8];
    const float* Wout    = (const float*)d_in[9];
    const float* bout    = (const float*)d_in[10];
    float* out = (float*)d_out;

    const int n    = in_sizes[0] / 6;
    const int E_tp = in_sizes[1] / 2;
    const int E_it = in_sizes[2] / 2;
    const int B    = (n + 1023) >> 10;   // buckets (<=256 for n<=262144)

    // workspace layout
    float* h0      = (float*)d_ws;                     // n*32
    float* h1      = h0 + (size_t)n * 32;              // n*32
    int*   deg_it  = (int*)(h1 + (size_t)n * 32);      // n
    int*   row_it  = deg_it + n;                       // n
    float* inv_cnt = (float*)(row_it + n);             // n
    int*   deg_tp  = (int*)(inv_cnt + n);              // n    (zeroed)
    int*   ctr     = deg_tp + n;                       // 1    (zeroed)
    int*   bcnt    = ctr + 1;                          // 256  (zeroed)
    int*   bbase   = bcnt + 256;                       // 257
    int*   bcursor = bbase + 257;                      // 256
    int*   row_tp  = bcursor + 256;                    // n
    int*   next_tp = row_tp + n;                       // n
    int*   col_it  = next_tp + n;                      // E_it
    int*   col_tp  = col_it + E_it;                    // E_tp
    // ebuf (E_it * 8 B = 25.6 MB) aliases d_out; consumed by csr_it_kernel
    // before agg/final touch d_out. aggbuf also aliases d_out (later phase).
    unsigned long long* ebuf = (unsigned long long*)d_out;
    float* aggbuf = (float*)d_out;

    hipMemsetAsync(deg_tp, 0, (size_t)(n + 1 + 256) * sizeof(int), stream);

    // it CSR via multisplit
    bucket_count_kernel<<<512, 256, 0, stream>>>(ei_it, E_it, B, bcnt);
    bucket_prefix_kernel<<<1, 256, 0, stream>>>(B, bcnt, bbase, bcursor);
    multisplit_kernel<<<(E_it + 2047) / 2048, 256, 0, stream>>>(ei_it, E_it, bcursor, ebuf);
    csr_it_kernel<<<B, 256, 0, stream>>>(n, ebuf, bbase, row_it, deg_it, inv_cnt, col_it);

    // tp CSR (small) via old path
    hist_tp_kernel<<<(E_tp + 255) / 256, 256, 0, stream>>>(ei_tp, E_tp, deg_tp);
    alloc_tp_kernel<<<(n + 255) / 256, 256, 0, stream>>>(n, deg_tp, row_tp, next_tp, ctr);
    fill_tp_kernel<<<(E_tp + 255) / 256, 256, 0, stream>>>(ei_tp, E_tp, next_tp, col_tp);

    const int agg_blocks  = (n + 3) / 4;
    const int gemm_blocks = (n + 255) / 256;

    agg6_kernel<<<agg_blocks, 256, 0, stream>>>(n, x, row_it, deg_it, col_it,
                                                row_tp, deg_tp, col_tp, inv_cnt, aggbuf);
    gemm_kernel<6, false><<<gemm_blocks, 128, 0, stream>>>(
        n, aggbuf, x,
        W0_rel, W0_rel + 192, W0_root, W0_root + 192, b0, b0 + 32, h0);

    float* hin  = h0;
    float* hout = h1;
    for (int l = 0; l < 4; l++) {
        agg32_kernel<<<agg_blocks, 256, 0, stream>>>(n, hin, row_it, deg_it, col_it,
                                                     row_tp, deg_tp, col_tp, inv_cnt, aggbuf);
        gemm_kernel<32, true><<<gemm_blocks, 128, 0, stream>>>(
            n, aggbuf, hin,
            W_rel + (size_t)l * 2048, W_rel + (size_t)l * 2048 + 1024,
            W_root + (size_t)l * 2048, W_root + (size_t)l * 2048 + 1024,
            b + (size_t)l * 64, b + (size_t)l * 64 + 32, hout);
        float* t = hin; hin = hout; hout = t;
    }

    final_kernel<<<(n + 127) / 128, 256, 0, stream>>>(n, hin, Wout, bout, out);
}